// Round 13
// baseline (519.547 us; speedup 1.0000x reference)
//
#include <hip/hip_runtime.h>
#include <hip/hip_bf16.h>
#include <math.h>

#define D_MODEL 4096
#define N_HEADS 128
#define LATENT  512
#define ROPE_D  64
#define HEAD_D  32
#define BATCH   2
#define SEQ     1024
#define NTOK    (BATCH*SEQ)

typedef unsigned short u16;
typedef __attribute__((ext_vector_type(8))) short bf16x8;
typedef __attribute__((ext_vector_type(4))) float f32x4;

__device__ __forceinline__ u16 f2bf(float f) {
    union { float f; unsigned u; } v; v.f = f;
    unsigned r = (v.u + 0x7fffu + ((v.u >> 16) & 1u)) >> 16;
    return (u16)r;
}

__device__ __forceinline__ void gl_lds16(const u16* g, u16* l) {
    __builtin_amdgcn_global_load_lds(
        (const __attribute__((address_space(1))) unsigned int*)g,
        (__attribute__((address_space(3))) unsigned int*)l, 16, 0, 0);
}

// ---- 32x32 cast+transpose tile: W[K][N] fp32 -> Wt[N][K] bf16 -------------
__device__ __forceinline__ void castT_tile(const float* __restrict__ W,
                                           u16* __restrict__ Wt,
                                           int K, int N, int jx, int jy,
                                           float (*tile)[33])
{
    const int tid = threadIdx.x;
    const int j0 = jx * 32, i0 = jy * 32;
    {
        int r = tid >> 3, c4 = (tid & 7) << 2;
        float4 v = *(const float4*)(W + (size_t)(i0 + r) * N + j0 + c4);
        tile[r][c4 + 0] = v.x; tile[r][c4 + 1] = v.y;
        tile[r][c4 + 2] = v.z; tile[r][c4 + 3] = v.w;
    }
    __syncthreads();
    {
        int n = tid >> 3, k4 = (tid & 7) << 2;
        u16 o[4] = { f2bf(tile[k4 + 0][n]), f2bf(tile[k4 + 1][n]),
                     f2bf(tile[k4 + 2][n]), f2bf(tile[k4 + 3][n]) };
        *(uint2*)(Wt + (size_t)(j0 + n) * K + i0 + k4) = *(uint2*)o;
    }
}

// ---- 64x64 bf16 transpose tile for v_c -> vt ------------------------------
__device__ __forceinline__ void vtrans_tile(const u16* __restrict__ vc,
                                            u16* __restrict__ vt,
                                            int c0, int s0, int b, u16* buf)
{
    u16 (*tile)[72] = reinterpret_cast<u16(*)[72]>(buf);
    const int tid = threadIdx.x;
    #pragma unroll
    for (int it = 0; it < 2; ++it) {
        int e = it * 256 + tid;
        int r = e >> 3, c8 = e & 7;
        *(bf16x8*)&tile[r][c8 * 8] =
            *(const bf16x8*)(vc + (size_t)(b * SEQ + s0 + r) * 8192 + c0 + c8 * 8);
    }
    __syncthreads();
    #pragma unroll
    for (int it = 0; it < 2; ++it) {
        int e = it * 256 + tid;
        int d = e >> 3, c8 = e & 7;
        u16 o[8];
        #pragma unroll
        for (int j = 0; j < 8; ++j) o[j] = tile[c8 * 8 + j][d];
        *(bf16x8*)(vt + (size_t)(b * D_MODEL + c0 + d) * SEQ + s0 + c8 * 8) = *(bf16x8*)o;
    }
}

// ---- m97 GEMM core (MODE: 0=bf16 C, 1=f32 C) ------------------------------
template<int MODE>
__device__ __forceinline__ void gemm_core(const u16* __restrict__ A,
                                          const u16* __restrict__ Bt,
                                          void* __restrict__ Cout,
                                          int N, int K, int lda, int ldb, int ldc,
                                          int bm, int bn, u16* As, u16* Bs)
{
    const int tid  = threadIdx.x;
    const int lane = tid & 63;
    const int wave = tid >> 6;
    const int wr = wave >> 1, wc = wave & 1;
    const int l15 = lane & 15, lg = lane >> 4;

    f32x4 acc[4][4];
    #pragma unroll
    for (int i = 0; i < 4; ++i)
        #pragma unroll
        for (int j = 0; j < 4; ++j) acc[i][j] = (f32x4){0.f, 0.f, 0.f, 0.f};

    for (int kt = 0; kt < K; kt += 64) {
        __syncthreads();
        #pragma unroll
        for (int i = 0; i < 4; ++i) {          // stage A
            int f = i * 256 + tid;
            int row = f >> 3, c = f & 7;
            int sc = c ^ (row & 7);
            gl_lds16(A + (size_t)(bm + row) * lda + kt + sc * 8, As + f * 8);
        }
        #pragma unroll
        for (int i = 0; i < 4; ++i) {          // stage B
            int f = i * 256 + tid;
            int row = f >> 3, c = f & 7;
            int sc = c ^ (row & 7);
            gl_lds16(Bt + (size_t)(bn + row) * ldb + kt + sc * 8, Bs + f * 8);
        }
        __syncthreads();

        #pragma unroll
        for (int t = 0; t < 2; ++t) {
            bf16x8 af[4], bf[4];
            #pragma unroll
            for (int fm = 0; fm < 4; ++fm) {
                int row = wr * 64 + fm * 16 + l15;
                int c = (t * 4 + lg) ^ (row & 7);
                af[fm] = *(const bf16x8*)(As + row * 64 + c * 8);
            }
            #pragma unroll
            for (int fn = 0; fn < 4; ++fn) {
                int row = wc * 64 + fn * 16 + l15;
                int c = (t * 4 + lg) ^ (row & 7);
                bf[fn] = *(const bf16x8*)(Bs + row * 64 + c * 8);
            }
            #pragma unroll
            for (int fm = 0; fm < 4; ++fm)
                #pragma unroll
                for (int fn = 0; fn < 4; ++fn)
                    acc[fm][fn] = __builtin_amdgcn_mfma_f32_16x16x32_bf16(
                        af[fm], bf[fn], acc[fm][fn], 0, 0, 0);
        }
    }

    #pragma unroll
    for (int fm = 0; fm < 4; ++fm)
        #pragma unroll
        for (int fn = 0; fn < 4; ++fn)
            #pragma unroll
            for (int ri = 0; ri < 4; ++ri) {
                int row = bm + wr * 64 + fm * 16 + 4 * lg + ri;
                int col = bn + wc * 64 + fn * 16 + l15;
                if (col < N) {
                    float v = acc[fm][fn][ri];
                    if (MODE == 1) ((float*)Cout)[(size_t)row * ldc + col] = v;
                    else           ((u16*)Cout)[(size_t)row * ldc + col] = f2bf(v);
                }
            }
}

// ---- standalone m97 GEMM (M-fastest XCD chunk mapping; nwg % 8 == 0) ------
template<int MODE>
__global__ __launch_bounds__(256)
void gemm_bf16(const u16* __restrict__ A, const u16* __restrict__ Bt,
               void* __restrict__ Cout, int N, int K,
               int lda, int ldb, int ldc)
{
    __shared__ __align__(16) u16 As[128 * 64];
    __shared__ __align__(16) u16 Bs[128 * 64];
    const int nwg  = gridDim.x * gridDim.y;
    const int orig = blockIdx.y * gridDim.x + blockIdx.x;
    const int swz  = (orig & 7) * (nwg >> 3) + (orig >> 3);
    const int bm = (swz % gridDim.y) * 128;
    const int bn = (swz / gridDim.y) * 128;
    gemm_core<MODE>(A, Bt, Cout, N, K, lda, ldb, ldc, bm, bn, As, Bs);
}

// ---- gemm1_fused: GEMM1 + Up/Wuq transposes [+ Wo^T when bigws] -----------
__global__ __launch_bounds__(256)
void gemm1_fused(const u16* __restrict__ xb, const u16* __restrict__ BigT,
                 u16* __restrict__ C_big,
                 const float* __restrict__ Wk_up, const float* __restrict__ Wv_up,
                 const float* __restrict__ Wq_up, const float* __restrict__ Wo,
                 u16* __restrict__ UpT, u16* __restrict__ WuqT,
                 u16* __restrict__ WoT)
{
    __shared__ __align__(16) u16 As[128 * 64];
    __shared__ __align__(16) u16 Bs[128 * 64];
    int id = blockIdx.x;
    if (id < 1168) {       // GEMM1: C_big = xb @ BigT^T (M=2048,N=9344,K=4096)
        const int swz = (id & 7) * 146 + (id >> 3);
        const int bm = (swz % 16) * 128;
        const int bn = (swz / 16) * 128;
        gemm_core<0>(xb, BigT, C_big, 9344, 4096, 4096, 4096, 9344, bm, bn, As, Bs);
        return;
    }
    id -= 1168;
    float (*tile)[33] = reinterpret_cast<float(*)[33]>(As);
    if (id < 2048) { castT_tile(Wk_up, UpT, 512, 4096, id & 127, id >> 7, tile); return; }
    id -= 2048;
    if (id < 2048) { castT_tile(Wv_up, UpT + (size_t)4096 * 512, 512, 4096, id & 127, id >> 7, tile); return; }
    id -= 2048;
    if (id < 2048) { castT_tile(Wq_up, WuqT, 512, 4096, id & 127, id >> 7, tile); return; }
    id -= 2048;
    // Wo^T trailing blocks (only present when bigws grid includes them)
    castT_tile(Wo, WoT, 4096, 4096, id & 127, id >> 7, tile);
}

// ---- prep: cast_x + GEMM1-feeding transposes + pad zeroing ---------------
__global__ __launch_bounds__(256)
void prep_kernel(const float* __restrict__ x, u16* __restrict__ xb,
                 const float* __restrict__ Wq_rope, const float* __restrict__ Wq_down,
                 const float* __restrict__ Wkv_down, const float* __restrict__ Wk_rope,
                 u16* __restrict__ BigT)
{
    __shared__ float tile[32][33];
    const int tid = threadIdx.x;
    int id = blockIdx.x;
    if (id < 4096) {                          // cast x -> bf16
        size_t i = ((size_t)id * 256 + tid) * 8;
        float4 a = *(const float4*)(x + i);
        float4 b = *(const float4*)(x + i + 4);
        u16 o[8] = {f2bf(a.x), f2bf(a.y), f2bf(a.z), f2bf(a.w),
                    f2bf(b.x), f2bf(b.y), f2bf(b.z), f2bf(b.w)};
        *(bf16x8*)(xb + i) = *(bf16x8*)o;
        return;
    }
    id -= 4096;
    if (id < 32768) { castT_tile(Wq_rope, BigT, 4096, 8192, id & 255, id >> 8, tile); return; }
    id -= 32768;
    if (id < 2048) { castT_tile(Wq_down, BigT + (size_t)8192 * 4096, 4096, 512, id & 15, id >> 4, tile); return; }
    id -= 2048;
    if (id < 2048) { castT_tile(Wkv_down, BigT + (size_t)8704 * 4096, 4096, 512, id & 15, id >> 4, tile); return; }
    id -= 2048;
    if (id < 256) { castT_tile(Wk_rope, BigT + (size_t)9216 * 4096, 4096, 64, id & 1, id >> 1, tile); return; }
    id -= 256;
    {   // zero pad rows 9280..9343 of BigT (id in [0,64))
        u16* dst = BigT + ((size_t)9280 + id) * 4096;
        bf16x8 z = (bf16x8){0, 0, 0, 0, 0, 0, 0, 0};
        *(bf16x8*)(dst + tid * 8) = z;
        *(bf16x8*)(dst + 2048 + tid * 8) = z;
    }
}

// ---- fused3a: GEMM2 only (k|v up-projection) ------------------------------
__global__ __launch_bounds__(256)
void fused3a_kernel(const u16* __restrict__ Cbig, const u16* __restrict__ UpT,
                    u16* __restrict__ C2)
{
    __shared__ __align__(16) u16 As[128 * 64];
    __shared__ __align__(16) u16 Bs[128 * 64];
    int id = blockIdx.x;
    const int swz = (id & 7) * 128 + (id >> 3);
    const int bm = (swz & 15) * 128, bn = (swz >> 4) * 128;
    gemm_core<0>(Cbig + 8704, UpT, C2, 8192, 512, 9344, 512, 8192, bm, bn, As, Bs);
}

// ---- fused3b: GEMM3 + vtrans [+ Wo^T when !bigws] ------------------------
__global__ __launch_bounds__(256)
void fused3b_kernel(const u16* __restrict__ Cbig, const u16* __restrict__ WuqT,
                    u16* __restrict__ q_c, const float* __restrict__ Wo,
                    u16* __restrict__ WoT, const u16* __restrict__ C2,
                    u16* __restrict__ vt, int woT_here)
{
    __shared__ __align__(16) u16 As[128 * 64];
    __shared__ __align__(16) u16 Bs[128 * 64];
    int id = blockIdx.x;
    if (id < 512) {        // GEMM3: q_c = c_q @ Wq_up^T
        const int swz = (id & 7) * 64 + (id >> 3);
        const int bm = (swz & 15) * 128, bn = (swz >> 4) * 128;
        gemm_core<0>(Cbig + 8192, WuqT, q_c, 4096, 512, 9344, 512, 4096, bm, bn, As, Bs);
        return;
    }
    id -= 512;
    if (id < 2048) {       // vtrans: 2048 tiles (64 c x 16 s x 2 b)
        int c0 = (id & 63) * 64, s0 = ((id >> 6) & 15) * 64, b = id >> 10;
        vtrans_tile(C2 + 4096, vt, c0, s0, b, As);
        return;
    }
    id -= 2048;
    if (woT_here) {        // Wo^T fallback when ws too small
        float (*tile)[33] = reinterpret_cast<float(*)[33]>(As);
        castT_tile(Wo, WoT, 4096, 4096, id & 127, id >> 7, tile);
    }
}

// ------- MFMA flash attention: QBLK=128, single-P-buffer (40KB LDS) --------
__global__ __launch_bounds__(256)
void attn_kernel(const u16* __restrict__ q_c, const u16* __restrict__ q_r,
                 const u16* __restrict__ k_c, const u16* __restrict__ k_r,
                 const u16* __restrict__ vt,  u16* __restrict__ attn_out)
{
    __shared__ __align__(16) u16 s_kc[2][64 * 32];
    __shared__ __align__(16) u16 s_kr[2][64 * 64];
    __shared__ __align__(16) u16 s_vt[2][32 * 64];
    __shared__ __align__(16) u16 s_p[4][16 * 64];   // shared by both q-sets

    const int tid  = threadIdx.x;
    const int lane = tid & 63;
    const int w    = tid >> 6;
    const int l15  = lane & 15, lg = lane >> 4;
    const int q0 = blockIdx.x * 128;
    const int h  = blockIdx.y;
    const int b  = blockIdx.z;
    const size_t bS = (size_t)b * SEQ;
    const int hc = h * HEAD_D;
    const float c2 = 0.1020620726159658f * 1.44269504088896f; // log2e/sqrt(96)

    const int qA = q0 + w * 16 + l15;
    const int qB = qA + 64;
    const bf16x8 qfA0 = *(const bf16x8*)(q_c + (bS + qA) * 4096 + hc + lg * 8);
    const bf16x8 qfA1 = *(const bf16x8*)(q_r + (bS + qA) * 9344 + h * ROPE_D + lg * 8);
    const bf16x8 qfA2 = *(const bf16x8*)(q_r + (bS + qA) * 9344 + h * ROPE_D + 32 + lg * 8);
    const bf16x8 qfB0 = *(const bf16x8*)(q_c + (bS + qB) * 4096 + hc + lg * 8);
    const bf16x8 qfB1 = *(const bf16x8*)(q_r + (bS + qB) * 9344 + h * ROPE_D + lg * 8);
    const bf16x8 qfB2 = *(const bf16x8*)(q_r + (bS + qB) * 9344 + h * ROPE_D + 32 + lg * 8);

    bf16x8 vone;
    {
        short o = (l15 == 0) ? (short)0x3F80 : (short)0;
        vone = (bf16x8){o, o, o, o, o, o, o, o};
    }

    float m2A = -1e30f, m2B = -1e30f;
    f32x4 oaccA[3], oaccB[3];
    #pragma unroll
    for (int i = 0; i < 3; ++i) {
        oaccA[i] = (f32x4){0.f, 0.f, 0.f, 0.f};
        oaccB[i] = (f32x4){0.f, 0.f, 0.f, 0.f};
    }

    auto stage = [&](int buf, int k0) {
        { int f = tid, r = f >> 2, c = f & 3;
          gl_lds16(k_c + (bS + k0 + r) * 8192 + hc + ((c ^ ((r >> 1) & 3)) << 3),
                   &s_kc[buf][f * 8]); }
        #pragma unroll
        for (int it = 0; it < 2; ++it) {
          int f = it * 256 + tid, r = f >> 3, c = f & 7;
          gl_lds16(k_r + (bS + k0 + r) * 9344 + ((c ^ (r & 7)) << 3),
                   &s_kr[buf][f * 8]); }
        { int f = tid, d = f >> 3, c = f & 7;
          gl_lds16(vt + ((size_t)b * D_MODEL + hc + d) * SEQ + k0 + ((c ^ (d & 7)) << 3),
                   &s_vt[buf][f * 8]); }
    };

    stage(0, 0);
    asm volatile("s_waitcnt vmcnt(0)" ::: "memory");
    __builtin_amdgcn_sched_barrier(0);
    __builtin_amdgcn_s_barrier();
    __builtin_amdgcn_sched_barrier(0);

    int cur = 0;
    for (int t = 0; t < SEQ / 64; ++t) {
        if (t + 1 < SEQ / 64) {
            stage(cur ^ 1, (t + 1) * 64);
            asm volatile("s_waitcnt vmcnt(4)" ::: "memory");
        } else {
            asm volatile("s_waitcnt vmcnt(0)" ::: "memory");
        }
        __builtin_amdgcn_sched_barrier(0);
        __builtin_amdgcn_s_barrier();            // (A) tile t visible everywhere
        __builtin_amdgcn_sched_barrier(0);

        f32x4 scA[4], scB[4];
        #pragma unroll
        for (int fc = 0; fc < 4; ++fc) {
            scA[fc] = (f32x4){0.f, 0.f, 0.f, 0.f};
            scB[fc] = (f32x4){0.f, 0.f, 0.f, 0.f};
        }
        __builtin_amdgcn_s_setprio(1);
        #pragma unroll
        for (int fc = 0; fc < 4; ++fc) {         // one kb read -> 2 MFMA
            int row = fc * 16 + l15;
            bf16x8 kb = *(const bf16x8*)&s_kc[cur][row * 32 + ((lg ^ ((row >> 1) & 3)) << 3)];
            scA[fc] = __builtin_amdgcn_mfma_f32_16x16x32_bf16(kb, qfA0, scA[fc], 0, 0, 0);
            scB[fc] = __builtin_amdgcn_mfma_f32_16x16x32_bf16(kb, qfB0, scB[fc], 0, 0, 0);
        }
        #pragma unroll
        for (int tt = 0; tt < 2; ++tt) {
            bf16x8 qa = tt ? qfA2 : qfA1;
            bf16x8 qb = tt ? qfB2 : qfB1;
            #pragma unroll
            for (int fc = 0; fc < 4; ++fc) {
                int row = fc * 16 + l15;
                bf16x8 kb = *(const bf16x8*)&s_kr[cur][row * 64 + (((tt * 4 + lg) ^ (row & 7)) << 3)];
                scA[fc] = __builtin_amdgcn_mfma_f32_16x16x32_bf16(kb, qa, scA[fc], 0, 0, 0);
                scB[fc] = __builtin_amdgcn_mfma_f32_16x16x32_bf16(kb, qb, scB[fc], 0, 0, 0);
            }
        }
        __builtin_amdgcn_s_setprio(0);

        // ---- per set: softmax -> P write (shared buffer) -> PV ----
        #pragma unroll
        for (int st = 0; st < 2; ++st) {
            f32x4* sc = st ? scB : scA;
            float& m2 = st ? m2B : m2A;
            f32x4* oacc = st ? oaccB : oaccA;

            float a0 = fmaxf(fmaxf(sc[0][0], sc[0][1]), sc[0][2]);
            float a1 = fmaxf(fmaxf(sc[0][3], sc[1][0]), sc[1][1]);
            float a2 = fmaxf(fmaxf(sc[1][2], sc[1][3]), sc[2][0]);
            float a3 = fmaxf(fmaxf(sc[2][1], sc[2][2]), sc[2][3]);
            float a4 = fmaxf(fmaxf(sc[3][0], sc[3][1]), sc[3][2]);
            float b0 = fmaxf(fmaxf(a0, a1), a2);
            float b1 = fmaxf(fmaxf(a3, a4), sc[3][3]);
            float lmx = fmaxf(b0, b1);
            if (!__all(lmx * c2 <= m2 + 8.f)) {
                float tmx = fmaxf(lmx, __shfl_xor(lmx, 16));
                tmx = fmaxf(tmx, __shfl_xor(tmx, 32));
                float mn = fmaxf(m2, tmx * c2);
                float corr = exp2f(m2 - mn);
                m2 = mn;
                #pragma unroll
                for (int ri = 0; ri < 4; ++ri) {
                    float cr = __shfl(corr, 4 * lg + ri);
                    oacc[0][ri] *= cr; oacc[1][ri] *= cr; oacc[2][ri] *= cr;
                }
            }
            unsigned pk0[4], pk1[4];
            #pragma unroll
            for (int fc = 0; fc < 4; ++fc) {
                float p0 = exp2f(fmaf(sc[fc][0], c2, -m2));
                float p1 = exp2f(fmaf(sc[fc][1], c2, -m2));
                float p2 = exp2f(fmaf(sc[fc][2], c2, -m2));
                float p3 = exp2f(fmaf(sc[fc][3], c2, -m2));
                asm("v_cvt_pk_bf16_f32 %0, %1, %2" : "=v"(pk0[fc]) : "v"(p0), "v"(p1));
                asm("v_cvt_pk_bf16_f32 %0, %1, %2" : "=v"(pk1[fc]) : "v"(p2), "v"(p3));
            }
            #pragma unroll
            for (int fc = 0; fc < 4; ++fc) {
                int ch = (2 * fc + (lg >> 1)) ^ (l15 & 7);
                *(uint2*)&s_p[w][l15 * 64 + ch * 8 + 4 * (lg & 1)] =
                    make_uint2(pk0[fc], pk1[fc]);
            }
            __builtin_amdgcn_s_setprio(1);
            #pragma unroll
            for (int t2 = 0; t2 < 2; ++t2) {
                bf16x8 pa = *(const bf16x8*)&s_p[w][l15 * 64 + (((t2 * 4 + lg) ^ (l15 & 7)) << 3)];
                #pragma unroll
                for (int fd = 0; fd < 2; ++fd) {
                    int row = fd * 16 + l15;
                    bf16x8 vb = *(const bf16x8*)&s_vt[cur][row * 64 + (((t2 * 4 + lg) ^ (row & 7)) << 3)];
                    oacc[fd] = __builtin_amdgcn_mfma_f32_16x16x32_bf16(pa, vb, oacc[fd], 0, 0, 0);
                }
                oacc[2] = __builtin_amdgcn_mfma_f32_16x16x32_bf16(pa, vone, oacc[2], 0, 0, 0);
            }
            __builtin_amdgcn_s_setprio(0);
        }

        asm volatile("s_waitcnt lgkmcnt(0)" ::: "memory");
        __builtin_amdgcn_sched_barrier(0);
        __builtin_amdgcn_s_barrier();            // (B) safe to restage
        __builtin_amdgcn_sched_barrier(0);
        cur ^= 1;
    }

    #pragma unroll
    for (int ri = 0; ri < 4; ++ri) {
        float lsA = __shfl(oaccA[2][ri], lg << 4);
        float lsB = __shfl(oaccB[2][ri], lg << 4);
        float invA = 1.f / lsA, invB = 1.f / lsB;
        int rowA = q0 + w * 16 + 4 * lg + ri;
        int rowB = rowA + 64;
        attn_out[(bS + rowA) * 4096 + hc + l15]      = f2bf(oaccA[0][ri] * invA);
        attn_out[(bS + rowA) * 4096 + hc + 16 + l15] = f2bf(oaccA[1][ri] * invA);
        attn_out[(bS + rowB) * 4096 + hc + l15]      = f2bf(oaccB[0][ri] * invB);
        attn_out[(bS + rowB) * 4096 + hc + 16 + l15] = f2bf(oaccB[1][ri] * invB);
    }
}

// ---------------------------------------------------------------------------
extern "C" void kernel_launch(void* const* d_in, const int* in_sizes, int n_in,
                              void* d_out, int out_size, void* d_ws, size_t ws_size,
                              hipStream_t stream)
{
    (void)in_sizes; (void)n_in; (void)out_size;

    const float* x        = (const float*)d_in[0];
    const float* Wq_down  = (const float*)d_in[1];
    const float* Wq_up    = (const float*)d_in[2];
    const float* Wq_rope  = (const float*)d_in[3];
    const float* Wkv_down = (const float*)d_in[4];
    const float* Wk_up    = (const float*)d_in[5];
    const float* Wv_up    = (const float*)d_in[6];
    const float* Wk_rope  = (const float*)d_in[7];
    const float* Wo       = (const float*)d_in[8];

    // base workspace (u16 units), ~179 MB
    u16* ws   = (u16*)d_ws;
    u16* xb   = ws;                                  //  8,388,608 (x bf16; later attn_out)
    u16* BigT = xb + (size_t)8388608;                // 38,797,312 (9472 x 4096)
    u16* UpT  = BigT + (size_t)38797312;             //  4,194,304 (8192 x 512)
    u16* WuqT = UpT + (size_t)4194304;               //  2,097,152 (4096 x 512)
    u16* C_big= WuqT + (size_t)2097152;              // 19,136,512 (2048 x 9344)
    u16* C2   = C_big + (size_t)19136512;            // 16,777,216 (2048 x 8192: k_c|v_c)
    u16* wend = C2 + (size_t)16777216;               // = 89,391,104 u16 used
    u16* vt   = BigT + (size_t)16777216;             //  (aliases BigT after GEMM1)
    u16* q_c  = BigT + (size_t)25165824;
    u16* attn_out = xb;

    // Wo^T placement: dedicated buffer if workspace allows, else alias BigT
    const int bigws = (ws_size >= ((size_t)89391104 + 16777216) * 2);
    u16* WoT = bigws ? wend : BigT;

    dim3 blk(256);

    // 1. prep: cast_x + GEMM1-feeding transposes (41280 blocks)
    hipLaunchKernelGGL(prep_kernel, dim3(41280), blk, 0, stream,
                       x, xb, Wq_rope, Wq_down, Wkv_down, Wk_rope, BigT);
    // 2. GEMM1 + Up/Wuq transposes [+ Wo^T when bigws]
    hipLaunchKernelGGL(gemm1_fused,
                       dim3(1168 + 6144 + (bigws ? 16384 : 0)), blk, 0, stream,
                       xb, BigT, C_big, Wk_up, Wv_up, Wq_up, Wo, UpT, WuqT, WoT);
    // 3a. GEMM2 (k_c|v_c)
    hipLaunchKernelGGL(fused3a_kernel, dim3(1024), blk, 0, stream,
                       C_big, UpT, C2);
    // 3b. GEMM3 + vtrans [+ Wo^T fallback]
    hipLaunchKernelGGL(fused3b_kernel,
                       dim3(512 + 2048 + (bigws ? 0 : 16384)), blk, 0, stream,
                       C_big, WuqT, q_c, Wo, WoT, C2, vt, bigws ? 0 : 1);
    // 4. attention (QBLK=128, 40KB LDS)
    hipLaunchKernelGGL(attn_kernel, dim3(8, 128, 2), blk, 0, stream,
                       q_c, C_big, C2, C_big + 9216, vt, attn_out);
    // 5. output projection (fp32 out)
    gemm_bf16<1><<<dim3(32, 16), blk, 0, stream>>>(
        attn_out, WoT, d_out, 4096, 4096, 4096, 4096, 4096);
}

// Round 14
// 507.351 us; speedup vs baseline: 1.0240x; 1.0240x over previous
//
#include <hip/hip_runtime.h>
#include <hip/hip_bf16.h>
#include <math.h>

#define D_MODEL 4096
#define N_HEADS 128
#define LATENT  512
#define ROPE_D  64
#define HEAD_D  32
#define BATCH   2
#define SEQ     1024
#define NTOK    (BATCH*SEQ)

typedef unsigned short u16;
typedef __attribute__((ext_vector_type(8))) short bf16x8;
typedef __attribute__((ext_vector_type(4))) float f32x4;

__device__ __forceinline__ u16 f2bf(float f) {
    union { float f; unsigned u; } v; v.f = f;
    unsigned r = (v.u + 0x7fffu + ((v.u >> 16) & 1u)) >> 16;
    return (u16)r;
}

__device__ __forceinline__ void gl_lds16(const u16* g, u16* l) {
    __builtin_amdgcn_global_load_lds(
        (const __attribute__((address_space(1))) unsigned int*)g,
        (__attribute__((address_space(3))) unsigned int*)l, 16, 0, 0);
}

// ---- 32x32 cast+transpose tile: W[K][N] fp32 -> Wt[N][K] bf16 -------------
__device__ __forceinline__ void castT_tile(const float* __restrict__ W,
                                           u16* __restrict__ Wt,
                                           int K, int N, int jx, int jy,
                                           float (*tile)[33])
{
    const int tid = threadIdx.x;
    const int j0 = jx * 32, i0 = jy * 32;
    {
        int r = tid >> 3, c4 = (tid & 7) << 2;
        float4 v = *(const float4*)(W + (size_t)(i0 + r) * N + j0 + c4);
        tile[r][c4 + 0] = v.x; tile[r][c4 + 1] = v.y;
        tile[r][c4 + 2] = v.z; tile[r][c4 + 3] = v.w;
    }
    __syncthreads();
    {
        int n = tid >> 3, k4 = (tid & 7) << 2;
        u16 o[4] = { f2bf(tile[k4 + 0][n]), f2bf(tile[k4 + 1][n]),
                     f2bf(tile[k4 + 2][n]), f2bf(tile[k4 + 3][n]) };
        *(uint2*)(Wt + (size_t)(j0 + n) * K + i0 + k4) = *(uint2*)o;
    }
}

// ---- m97 GEMM core (MODE: 0=bf16 C, 1=f32 C) ------------------------------
template<int MODE>
__device__ __forceinline__ void gemm_core(const u16* __restrict__ A,
                                          const u16* __restrict__ Bt,
                                          void* __restrict__ Cout,
                                          int N, int K, int lda, int ldb, int ldc,
                                          int bm, int bn, u16* As, u16* Bs)
{
    const int tid  = threadIdx.x;
    const int lane = tid & 63;
    const int wave = tid >> 6;
    const int wr = wave >> 1, wc = wave & 1;
    const int l15 = lane & 15, lg = lane >> 4;

    f32x4 acc[4][4];
    #pragma unroll
    for (int i = 0; i < 4; ++i)
        #pragma unroll
        for (int j = 0; j < 4; ++j) acc[i][j] = (f32x4){0.f, 0.f, 0.f, 0.f};

    for (int kt = 0; kt < K; kt += 64) {
        __syncthreads();
        #pragma unroll
        for (int i = 0; i < 4; ++i) {          // stage A
            int f = i * 256 + tid;
            int row = f >> 3, c = f & 7;
            int sc = c ^ (row & 7);
            gl_lds16(A + (size_t)(bm + row) * lda + kt + sc * 8, As + f * 8);
        }
        #pragma unroll
        for (int i = 0; i < 4; ++i) {          // stage B
            int f = i * 256 + tid;
            int row = f >> 3, c = f & 7;
            int sc = c ^ (row & 7);
            gl_lds16(Bt + (size_t)(bn + row) * ldb + kt + sc * 8, Bs + f * 8);
        }
        __syncthreads();

        #pragma unroll
        for (int t = 0; t < 2; ++t) {
            bf16x8 af[4], bf[4];
            #pragma unroll
            for (int fm = 0; fm < 4; ++fm) {
                int row = wr * 64 + fm * 16 + l15;
                int c = (t * 4 + lg) ^ (row & 7);
                af[fm] = *(const bf16x8*)(As + row * 64 + c * 8);
            }
            #pragma unroll
            for (int fn = 0; fn < 4; ++fn) {
                int row = wc * 64 + fn * 16 + l15;
                int c = (t * 4 + lg) ^ (row & 7);
                bf[fn] = *(const bf16x8*)(Bs + row * 64 + c * 8);
            }
            #pragma unroll
            for (int fm = 0; fm < 4; ++fm)
                #pragma unroll
                for (int fn = 0; fn < 4; ++fn)
                    acc[fm][fn] = __builtin_amdgcn_mfma_f32_16x16x32_bf16(
                        af[fm], bf[fn], acc[fm][fn], 0, 0, 0);
        }
    }

    #pragma unroll
    for (int fm = 0; fm < 4; ++fm)
        #pragma unroll
        for (int fn = 0; fn < 4; ++fn)
            #pragma unroll
            for (int ri = 0; ri < 4; ++ri) {
                int row = bm + wr * 64 + fm * 16 + 4 * lg + ri;
                int col = bn + wc * 64 + fn * 16 + l15;
                if (col < N) {
                    float v = acc[fm][fn][ri];
                    if (MODE == 1) ((float*)Cout)[(size_t)row * ldc + col] = v;
                    else           ((u16*)Cout)[(size_t)row * ldc + col] = f2bf(v);
                }
            }
}

// ---- standalone m97 GEMM (M-fastest XCD chunk mapping; nwg % 8 == 0) ------
template<int MODE>
__global__ __launch_bounds__(256)
void gemm_bf16(const u16* __restrict__ A, const u16* __restrict__ Bt,
               void* __restrict__ Cout, int N, int K,
               int lda, int ldb, int ldc)
{
    __shared__ __align__(16) u16 As[128 * 64];
    __shared__ __align__(16) u16 Bs[128 * 64];
    const int nwg  = gridDim.x * gridDim.y;
    const int orig = blockIdx.y * gridDim.x + blockIdx.x;
    const int swz  = (orig & 7) * (nwg >> 3) + (orig >> 3);
    const int bm = (swz % gridDim.y) * 128;
    const int bn = (swz / gridDim.y) * 128;
    gemm_core<MODE>(A, Bt, Cout, N, K, lda, ldb, ldc, bm, bn, As, Bs);
}

// ---- gemm1_fused: GEMM1 (1168 blk) + Up/Wuq weight transposes (trailing) --
__global__ __launch_bounds__(256)
void gemm1_fused(const u16* __restrict__ xb, const u16* __restrict__ BigT,
                 u16* __restrict__ C_big,
                 const float* __restrict__ Wk_up, const float* __restrict__ Wv_up,
                 const float* __restrict__ Wq_up,
                 u16* __restrict__ UpT, u16* __restrict__ WuqT)
{
    __shared__ __align__(16) u16 As[128 * 64];
    __shared__ __align__(16) u16 Bs[128 * 64];
    int id = blockIdx.x;
    if (id < 1168) {       // GEMM1: C_big = xb @ BigT^T (M=2048,N=9344,K=4096)
        const int swz = (id & 7) * 146 + (id >> 3);
        const int bm = (swz % 16) * 128;
        const int bn = (swz / 16) * 128;
        gemm_core<0>(xb, BigT, C_big, 9344, 4096, 4096, 4096, 9344, bm, bn, As, Bs);
        return;
    }
    id -= 1168;
    float (*tile)[33] = reinterpret_cast<float(*)[33]>(As);
    if (id < 2048) { castT_tile(Wk_up, UpT, 512, 4096, id & 127, id >> 7, tile); return; }
    id -= 2048;
    if (id < 2048) { castT_tile(Wv_up, UpT + (size_t)4096 * 512, 512, 4096, id & 127, id >> 7, tile); return; }
    id -= 2048;
    castT_tile(Wq_up, WuqT, 512, 4096, id & 127, id >> 7, tile);
}

// ---- prep: cast_x + GEMM1-feeding transposes + pad zeroing ---------------
__global__ __launch_bounds__(256)
void prep_kernel(const float* __restrict__ x, u16* __restrict__ xb,
                 const float* __restrict__ Wq_rope, const float* __restrict__ Wq_down,
                 const float* __restrict__ Wkv_down, const float* __restrict__ Wk_rope,
                 u16* __restrict__ BigT)
{
    __shared__ float tile[32][33];
    const int tid = threadIdx.x;
    int id = blockIdx.x;
    if (id < 4096) {                          // cast x -> bf16
        size_t i = ((size_t)id * 256 + tid) * 8;
        float4 a = *(const float4*)(x + i);
        float4 b = *(const float4*)(x + i + 4);
        u16 o[8] = {f2bf(a.x), f2bf(a.y), f2bf(a.z), f2bf(a.w),
                    f2bf(b.x), f2bf(b.y), f2bf(b.z), f2bf(b.w)};
        *(bf16x8*)(xb + i) = *(bf16x8*)o;
        return;
    }
    id -= 4096;
    if (id < 32768) { castT_tile(Wq_rope, BigT, 4096, 8192, id & 255, id >> 8, tile); return; }
    id -= 32768;
    if (id < 2048) { castT_tile(Wq_down, BigT + (size_t)8192 * 4096, 4096, 512, id & 15, id >> 4, tile); return; }
    id -= 2048;
    if (id < 2048) { castT_tile(Wkv_down, BigT + (size_t)8704 * 4096, 4096, 512, id & 15, id >> 4, tile); return; }
    id -= 2048;
    if (id < 256) { castT_tile(Wk_rope, BigT + (size_t)9216 * 4096, 4096, 64, id & 1, id >> 1, tile); return; }
    id -= 256;
    {   // zero pad rows 9280..9343 of BigT (id in [0,64))
        u16* dst = BigT + ((size_t)9280 + id) * 4096;
        bf16x8 z = (bf16x8){0, 0, 0, 0, 0, 0, 0, 0};
        *(bf16x8*)(dst + tid * 8) = z;
        *(bf16x8*)(dst + 2048 + tid * 8) = z;
    }
}

// ---- fused2: GEMM2 (k|v up) + GEMM3 (q up) + Wo^T transpose, ONE dispatch -
__global__ __launch_bounds__(256)
void fused2_kernel(const u16* __restrict__ Cbig, const u16* __restrict__ UpT,
                   u16* __restrict__ C2, const u16* __restrict__ WuqT,
                   u16* __restrict__ q_c, const float* __restrict__ Wo,
                   u16* __restrict__ WoT)
{
    __shared__ __align__(16) u16 As[128 * 64];
    __shared__ __align__(16) u16 Bs[128 * 64];
    int id = blockIdx.x;
    if (id < 1024) {       // GEMM2: k_c|v_c = c_kv @ [Wk_up|Wv_up]^T
        const int swz = (id & 7) * 128 + (id >> 3);
        const int bm = (swz & 15) * 128, bn = (swz >> 4) * 128;
        gemm_core<0>(Cbig + 8704, UpT, C2, 8192, 512, 9344, 512, 8192, bm, bn, As, Bs);
        return;
    }
    id -= 1024;
    if (id < 512) {        // GEMM3: q_c = c_q @ Wq_up^T
        const int swz = (id & 7) * 64 + (id >> 3);
        const int bm = (swz & 15) * 128, bn = (swz >> 4) * 128;
        gemm_core<0>(Cbig + 8192, WuqT, q_c, 4096, 512, 9344, 512, 4096, bm, bn, As, Bs);
        return;
    }
    id -= 512;
    {                      // Wo^T: 4096x4096, 16384 tiles
        float (*tile)[33] = reinterpret_cast<float(*)[33]>(As);
        castT_tile(Wo, WoT, 4096, 4096, id & 127, id >> 7, tile);
    }
}

// ---------- transpose v_c (in C2, stride 8192, col base 4096) -> vt --------
__global__ __launch_bounds__(256)
void vtrans_kernel(const u16* __restrict__ vc, u16* __restrict__ vt)
{
    __shared__ __align__(16) u16 tile[64][72];
    const int tid = threadIdx.x;
    const int c0 = blockIdx.x * 64;
    const int s0 = blockIdx.y * 64;
    const int b  = blockIdx.z;
    #pragma unroll
    for (int it = 0; it < 2; ++it) {
        int e = it * 256 + tid;
        int r = e >> 3, c8 = e & 7;
        *(bf16x8*)&tile[r][c8 * 8] =
            *(const bf16x8*)(vc + (size_t)(b * SEQ + s0 + r) * 8192 + c0 + c8 * 8);
    }
    __syncthreads();
    #pragma unroll
    for (int it = 0; it < 2; ++it) {
        int e = it * 256 + tid;
        int d = e >> 3, c8 = e & 7;
        u16 o[8];
        #pragma unroll
        for (int j = 0; j < 8; ++j) o[j] = tile[c8 * 8 + j][d];
        *(bf16x8*)(vt + (size_t)(b * D_MODEL + c0 + d) * SEQ + s0 + c8 * 8) = *(bf16x8*)o;
    }
}

// ------- MFMA flash attention: QBLK=128, 2 q-sets/wave (LDS-read amortize) -
__global__ __launch_bounds__(256)
void attn_kernel(const u16* __restrict__ q_c, const u16* __restrict__ q_r,
                 const u16* __restrict__ k_c, const u16* __restrict__ k_r,
                 const u16* __restrict__ vt,  u16* __restrict__ attn_out)
{
    __shared__ __align__(16) u16 s_kc[2][64 * 32];
    __shared__ __align__(16) u16 s_kr[2][64 * 64];
    __shared__ __align__(16) u16 s_vt[2][32 * 64];
    __shared__ __align__(16) u16 s_p[4][2][16 * 64];

    const int tid  = threadIdx.x;
    const int lane = tid & 63;
    const int w    = tid >> 6;
    const int l15  = lane & 15, lg = lane >> 4;
    const int q0 = blockIdx.x * 128;
    const int h  = blockIdx.y;
    const int b  = blockIdx.z;
    const size_t bS = (size_t)b * SEQ;
    const int hc = h * HEAD_D;
    const float c2 = 0.1020620726159658f * 1.44269504088896f; // log2e/sqrt(96)

    const int qA = q0 + w * 16 + l15;
    const int qB = qA + 64;
    const bf16x8 qfA0 = *(const bf16x8*)(q_c + (bS + qA) * 4096 + hc + lg * 8);
    const bf16x8 qfA1 = *(const bf16x8*)(q_r + (bS + qA) * 9344 + h * ROPE_D + lg * 8);
    const bf16x8 qfA2 = *(const bf16x8*)(q_r + (bS + qA) * 9344 + h * ROPE_D + 32 + lg * 8);
    const bf16x8 qfB0 = *(const bf16x8*)(q_c + (bS + qB) * 4096 + hc + lg * 8);
    const bf16x8 qfB1 = *(const bf16x8*)(q_r + (bS + qB) * 9344 + h * ROPE_D + lg * 8);
    const bf16x8 qfB2 = *(const bf16x8*)(q_r + (bS + qB) * 9344 + h * ROPE_D + 32 + lg * 8);

    // constant ones B-fragment (col 0 of the virtual ones-V): no LDS needed
    bf16x8 vone;
    {
        short o = (l15 == 0) ? (short)0x3F80 : (short)0;
        vone = (bf16x8){o, o, o, o, o, o, o, o};
    }

    float m2A = -1e30f, m2B = -1e30f;
    f32x4 oaccA[3], oaccB[3];
    #pragma unroll
    for (int i = 0; i < 3; ++i) {
        oaccA[i] = (f32x4){0.f, 0.f, 0.f, 0.f};
        oaccB[i] = (f32x4){0.f, 0.f, 0.f, 0.f};
    }

    auto stage = [&](int buf, int k0) {
        { int f = tid, r = f >> 2, c = f & 3;
          gl_lds16(k_c + (bS + k0 + r) * 8192 + hc + ((c ^ ((r >> 1) & 3)) << 3),
                   &s_kc[buf][f * 8]); }
        #pragma unroll
        for (int it = 0; it < 2; ++it) {
          int f = it * 256 + tid, r = f >> 3, c = f & 7;
          gl_lds16(k_r + (bS + k0 + r) * 9344 + ((c ^ (r & 7)) << 3),
                   &s_kr[buf][f * 8]); }
        { int f = tid, d = f >> 3, c = f & 7;
          gl_lds16(vt + ((size_t)b * D_MODEL + hc + d) * SEQ + k0 + ((c ^ (d & 7)) << 3),
                   &s_vt[buf][f * 8]); }
    };

    stage(0, 0);
    asm volatile("s_waitcnt vmcnt(0)" ::: "memory");
    __builtin_amdgcn_sched_barrier(0);
    __builtin_amdgcn_s_barrier();
    __builtin_amdgcn_sched_barrier(0);

    int cur = 0;
    for (int t = 0; t < SEQ / 64; ++t) {
        if (t + 1 < SEQ / 64) {
            stage(cur ^ 1, (t + 1) * 64);
            asm volatile("s_waitcnt vmcnt(4)" ::: "memory");
        } else {
            asm volatile("s_waitcnt vmcnt(0)" ::: "memory");
        }
        __builtin_amdgcn_sched_barrier(0);
        __builtin_amdgcn_s_barrier();            // (A) tile t visible everywhere
        __builtin_amdgcn_sched_barrier(0);

        f32x4 scA[4], scB[4];
        #pragma unroll
        for (int fc = 0; fc < 4; ++fc) {
            scA[fc] = (f32x4){0.f, 0.f, 0.f, 0.f};
            scB[fc] = (f32x4){0.f, 0.f, 0.f, 0.f};
        }
        __builtin_amdgcn_s_setprio(1);
        #pragma unroll
        for (int fc = 0; fc < 4; ++fc) {         // one kb read -> 2 MFMA
            int row = fc * 16 + l15;
            bf16x8 kb = *(const bf16x8*)&s_kc[cur][row * 32 + ((lg ^ ((row >> 1) & 3)) << 3)];
            scA[fc] = __builtin_amdgcn_mfma_f32_16x16x32_bf16(kb, qfA0, scA[fc], 0, 0, 0);
            scB[fc] = __builtin_amdgcn_mfma_f32_16x16x32_bf16(kb, qfB0, scB[fc], 0, 0, 0);
        }
        #pragma unroll
        for (int tt = 0; tt < 2; ++tt) {
            bf16x8 qa = tt ? qfA2 : qfA1;
            bf16x8 qb = tt ? qfB2 : qfB1;
            #pragma unroll
            for (int fc = 0; fc < 4; ++fc) {
                int row = fc * 16 + l15;
                bf16x8 kb = *(const bf16x8*)&s_kr[cur][row * 64 + (((tt * 4 + lg) ^ (row & 7)) << 3)];
                scA[fc] = __builtin_amdgcn_mfma_f32_16x16x32_bf16(kb, qa, scA[fc], 0, 0, 0);
                scB[fc] = __builtin_amdgcn_mfma_f32_16x16x32_bf16(kb, qb, scB[fc], 0, 0, 0);
            }
        }
        __builtin_amdgcn_s_setprio(0);

        // ---- softmax per set (cheap defer check: shuffles only on rescale)
        #pragma unroll
        for (int st = 0; st < 2; ++st) {
            f32x4* sc = st ? scB : scA;
            float& m2 = st ? m2B : m2A;
            f32x4* oacc = st ? oaccB : oaccA;

            float a0 = fmaxf(fmaxf(sc[0][0], sc[0][1]), sc[0][2]);
            float a1 = fmaxf(fmaxf(sc[0][3], sc[1][0]), sc[1][1]);
            float a2 = fmaxf(fmaxf(sc[1][2], sc[1][3]), sc[2][0]);
            float a3 = fmaxf(fmaxf(sc[2][1], sc[2][2]), sc[2][3]);
            float a4 = fmaxf(fmaxf(sc[3][0], sc[3][1]), sc[3][2]);
            float b0 = fmaxf(fmaxf(a0, a1), a2);
            float b1 = fmaxf(fmaxf(a3, a4), sc[3][3]);
            float lmx = fmaxf(b0, b1);             // per-lane max (16 vals)
            if (!__all(lmx * c2 <= m2 + 8.f)) {    // == global check via __all
                float tmx = fmaxf(lmx, __shfl_xor(lmx, 16));
                tmx = fmaxf(tmx, __shfl_xor(tmx, 32));
                float mn = fmaxf(m2, tmx * c2);
                float corr = exp2f(m2 - mn);
                m2 = mn;
                #pragma unroll
                for (int ri = 0; ri < 4; ++ri) {
                    float cr = __shfl(corr, 4 * lg + ri);
                    oacc[0][ri] *= cr; oacc[1][ri] *= cr; oacc[2][ri] *= cr;
                }
            }
            unsigned pk0[4], pk1[4];
            #pragma unroll
            for (int fc = 0; fc < 4; ++fc) {
                float p0 = exp2f(fmaf(sc[fc][0], c2, -m2));
                float p1 = exp2f(fmaf(sc[fc][1], c2, -m2));
                float p2 = exp2f(fmaf(sc[fc][2], c2, -m2));
                float p3 = exp2f(fmaf(sc[fc][3], c2, -m2));
                asm("v_cvt_pk_bf16_f32 %0, %1, %2" : "=v"(pk0[fc]) : "v"(p0), "v"(p1));
                asm("v_cvt_pk_bf16_f32 %0, %1, %2" : "=v"(pk1[fc]) : "v"(p2), "v"(p3));
            }
            #pragma unroll
            for (int fc = 0; fc < 4; ++fc) {
                int ch = (2 * fc + (lg >> 1)) ^ (l15 & 7);
                *(uint2*)&s_p[w][st][l15 * 64 + ch * 8 + 4 * (lg & 1)] =
                    make_uint2(pk0[fc], pk1[fc]);
            }
        }

        // ---- PV: shared vb reads feed both sets; ones-col in registers ----
        __builtin_amdgcn_s_setprio(1);
        #pragma unroll
        for (int t2 = 0; t2 < 2; ++t2) {
            int pofs = (((t2 * 4 + lg) ^ (l15 & 7)) << 3);
            bf16x8 paA = *(const bf16x8*)&s_p[w][0][l15 * 64 + pofs];
            bf16x8 paB = *(const bf16x8*)&s_p[w][1][l15 * 64 + pofs];
            #pragma unroll
            for (int fd = 0; fd < 2; ++fd) {
                int row = fd * 16 + l15;
                bf16x8 vb = *(const bf16x8*)&s_vt[cur][row * 64 + (((t2 * 4 + lg) ^ (row & 7)) << 3)];
                oaccA[fd] = __builtin_amdgcn_mfma_f32_16x16x32_bf16(paA, vb, oaccA[fd], 0, 0, 0);
                oaccB[fd] = __builtin_amdgcn_mfma_f32_16x16x32_bf16(paB, vb, oaccB[fd], 0, 0, 0);
            }
            oaccA[2] = __builtin_amdgcn_mfma_f32_16x16x32_bf16(paA, vone, oaccA[2], 0, 0, 0);
            oaccB[2] = __builtin_amdgcn_mfma_f32_16x16x32_bf16(paB, vone, oaccB[2], 0, 0, 0);
        }
        __builtin_amdgcn_s_setprio(0);

        asm volatile("s_waitcnt lgkmcnt(0)" ::: "memory");
        __builtin_amdgcn_sched_barrier(0);
        __builtin_amdgcn_s_barrier();            // (B) safe to restage
        __builtin_amdgcn_sched_barrier(0);
        cur ^= 1;
    }

    #pragma unroll
    for (int ri = 0; ri < 4; ++ri) {
        float lsA = __shfl(oaccA[2][ri], lg << 4);
        float lsB = __shfl(oaccB[2][ri], lg << 4);
        float invA = 1.f / lsA, invB = 1.f / lsB;
        int rowA = q0 + w * 16 + 4 * lg + ri;
        int rowB = rowA + 64;
        attn_out[(bS + rowA) * 4096 + hc + l15]      = f2bf(oaccA[0][ri] * invA);
        attn_out[(bS + rowA) * 4096 + hc + 16 + l15] = f2bf(oaccA[1][ri] * invA);
        attn_out[(bS + rowB) * 4096 + hc + l15]      = f2bf(oaccB[0][ri] * invB);
        attn_out[(bS + rowB) * 4096 + hc + 16 + l15] = f2bf(oaccB[1][ri] * invB);
    }
}

// ---------------------------------------------------------------------------
extern "C" void kernel_launch(void* const* d_in, const int* in_sizes, int n_in,
                              void* d_out, int out_size, void* d_ws, size_t ws_size,
                              hipStream_t stream)
{
    (void)in_sizes; (void)n_in; (void)out_size; (void)ws_size;

    const float* x        = (const float*)d_in[0];
    const float* Wq_down  = (const float*)d_in[1];
    const float* Wq_up    = (const float*)d_in[2];
    const float* Wq_rope  = (const float*)d_in[3];
    const float* Wkv_down = (const float*)d_in[4];
    const float* Wk_up    = (const float*)d_in[5];
    const float* Wv_up    = (const float*)d_in[6];
    const float* Wk_rope  = (const float*)d_in[7];
    const float* Wo       = (const float*)d_in[8];

    // workspace (u16 units), ~170 MB total
    u16* ws   = (u16*)d_ws;
    u16* xb   = ws;                                  //  8,388,608 (x bf16; later attn_out)
    u16* BigT = xb + (size_t)8388608;                // 38,797,312 (9472 x 4096)
    u16* UpT  = BigT + (size_t)38797312;             //  4,194,304 (8192 x 512)
    u16* WuqT = UpT + (size_t)4194304;               //  2,097,152 (4096 x 512)
    u16* C_big= WuqT + (size_t)2097152;              // 19,136,512 (2048 x 9344)
    u16* C2   = C_big + (size_t)19136512;            // 16,777,216 (2048 x 8192: k_c|v_c)
    u16* WoT  = BigT;                                // after GEMM1
    u16* vt   = BigT + (size_t)16777216;             //  8,388,608 (2 x 4096 x 1024)
    u16* q_c  = BigT + (size_t)25165824;             //  8,388,608 (2048 x 4096)
    u16* attn_out = xb;

    dim3 blk(256);

    // 1. prep: cast_x + GEMM1-feeding transposes (41280 blocks)
    hipLaunchKernelGGL(prep_kernel, dim3(41280), blk, 0, stream,
                       x, xb, Wq_rope, Wq_down, Wkv_down, Wk_rope, BigT);
    // 2. GEMM1 + independent Up-weight transposes in one dispatch
    hipLaunchKernelGGL(gemm1_fused, dim3(1168 + 6144), blk, 0, stream,
                       xb, BigT, C_big, Wk_up, Wv_up, Wq_up, UpT, WuqT);
    // 3. GEMM2 + GEMM3 + Wo^T in one dispatch
    hipLaunchKernelGGL(fused2_kernel, dim3(1024 + 512 + 16384), blk, 0, stream,
                       C_big, UpT, C2, WuqT, q_c, Wo, WoT);
    // 4. V transpose
    hipLaunchKernelGGL(vtrans_kernel, dim3(64, 16, 2), blk, 0, stream, C2 + 4096, vt);
    // 5. attention (QBLK=128)
    hipLaunchKernelGGL(attn_kernel, dim3(8, 128, 2), blk, 0, stream,
                       q_c, C_big, C2, C_big + 9216, vt, attn_out);
    // 6. output projection (fp32 out)
    gemm_bf16<1><<<dim3(32, 16), blk, 0, stream>>>(
        attn_out, WoT, d_out, 4096, 4096, 4096, 4096, 4096);
}